// Round 1
// baseline (406.280 us; speedup 1.0000x reference)
//
#include <hip/hip_runtime.h>

#define H_ 64
#define W_ 2048
#define HWsz (H_*W_)
#define CIN 64
#define CTOT 68
#define COUT 64

typedef float f32x4 __attribute__((ext_vector_type(4)));
typedef short s16x8 __attribute__((ext_vector_type(8)));

__device__ __forceinline__ unsigned short f2bf(float f) {
    unsigned u = __builtin_bit_cast(unsigned, f);
    unsigned r = u + 0x7fffu + ((u >> 16) & 1u);   // RNE; inputs are finite
    return (unsigned short)(r >> 16);
}

// ---------------- prep: fold BN constants, Wagg -> bf16 ----------------
__global__ __launch_bounds__(256) void prep_k(
    const float* __restrict__ W1, const float* __restrict__ g1,
    const float* __restrict__ b1, const float* __restrict__ m1,
    const float* __restrict__ v1, const float* __restrict__ W2,
    const float* __restrict__ Wagg, const float* __restrict__ g2,
    const float* __restrict__ bb2, const float* __restrict__ m2,
    const float* __restrict__ v2,
    float* __restrict__ W1s, float* __restrict__ t1, float* __restrict__ W2c,
    float* __restrict__ s2, float* __restrict__ t2,
    unsigned short* __restrict__ Bw)
{
    int tid = threadIdx.x;
    if (tid < 64) {
        float s1 = g1[tid] * rsqrtf(v1[tid] + 1e-5f);
        t1[tid]  = b1[tid] - m1[tid] * s1;
        W2c[tid] = W2[tid];
        float s2v = g2[tid] * rsqrtf(v2[tid] + 1e-5f);
        s2[tid] = s2v;
        t2[tid] = bb2[tid] - m2[tid] * s2v;
#pragma unroll
        for (int m = 0; m < 4; ++m) W1s[tid*4+m] = W1[tid*4+m] * s1;
    }
    for (int i = tid; i < COUT*9*CIN; i += 256)
        Bw[i] = f2bf(Wagg[i]);
}

// ---------------- logits + masked softmax -> 9 fp32 weights / pixel ----------------
__global__ __launch_bounds__(256) void wsoft_k(
    const float* __restrict__ x, const int* __restrict__ mask,
    const float* __restrict__ W1s, const float* __restrict__ t1,
    const float* __restrict__ W2c, const float* __restrict__ b2p,
    float* __restrict__ wbuf)
{
    int p = blockIdx.x * 256 + threadIdx.x;
    int w = p & (W_-1);
    int h = (p >> 11) & (H_-1);
    int b = p >> 17;
    const float* xb = x + (size_t)b * CTOT * HWsz;

    float pc[4];
#pragma unroll
    for (int m = 0; m < 4; ++m) pc[m] = xb[m*HWsz + h*W_ + w];

    float d[9][4]; float mu[9];
#pragma unroll
    for (int k = 0; k < 9; ++k) {
        int ih = h + k/3 - 1, iw = w + k%3 - 1;
        bool ok = ((unsigned)ih < (unsigned)H_) && ((unsigned)iw < (unsigned)W_);
        if (ok) {
#pragma unroll
            for (int m = 0; m < 4; ++m) d[k][m] = xb[m*HWsz + ih*W_ + iw] - pc[m];
            mu[k] = (float)mask[(b*H_ + ih)*W_ + iw];
        } else {
#pragma unroll
            for (int m = 0; m < 4; ++m) d[k][m] = 0.f;
            mu[k] = 0.f;
        }
    }

    float lg[9];
#pragma unroll
    for (int k = 0; k < 9; ++k) lg[k] = 0.f;

    for (int c = 0; c < CIN; ++c) {
        const float4 wv = *(const float4*)(W1s + 4*c);
        float t1c = t1[c], w2c = W2c[c];
#pragma unroll
        for (int k = 0; k < 9; ++k) {
            float v = fmaf(d[k][0], wv.x, fmaf(d[k][1], wv.y,
                      fmaf(d[k][2], wv.z, fmaf(d[k][3], wv.w, t1c))));
            lg[k] += fmaxf(v, 0.f) * w2c;
        }
    }

    float b2v = b2p[0];
    float mx = -1e30f;
#pragma unroll
    for (int k = 0; k < 9; ++k) { lg[k] = (lg[k] + b2v) * mu[k]; mx = fmaxf(mx, lg[k]); }
    float s = 0.f, e[9];
#pragma unroll
    for (int k = 0; k < 9; ++k) { e[k] = __expf(lg[k] - mx); s += e[k]; }
    float inv = 1.f / s;
    int bh = b*H_ + h;
#pragma unroll
    for (int k = 0; k < 9; ++k)
        wbuf[((size_t)bh*9 + k)*W_ + w] = e[k] * inv;
}

// ---------------- MFMA aggregation: y[o] = BN2(ReLU(sum_k w_k * Wagg_k . f(p+dk))) ----------------
// Block: 256 thr (4 waves), tile = 128 pixels along W (one row) x 64 outputs.
// Wave wv: pixels [wv*32, wv*32+32) x all 64 outputs, 16x16x32 bf16 MFMA.
// Per neighbor k: 2 K-chunks of 32 ch into tmp acc, then fin += w_k(row) * tmp.
__global__ __launch_bounds__(256) void agg_k(
    const float* __restrict__ x,
    const unsigned short* __restrict__ Bw,
    const float* __restrict__ wbuf,
    const float* __restrict__ s2, const float* __restrict__ t2,
    float* __restrict__ out)
{
    // feats halo tile: 3 rows x 130 cols x (64ch + 8 pad) bf16 = 56,160 B
    __shared__ __align__(16) unsigned short fe[3][130][72];
    __shared__ __align__(16) float wl[9][128];        // 4,608 B

    int tid = threadIdx.x;
    int bx = blockIdx.x, by = blockIdx.y;
    int b = by >> 6, h = by & 63;
    int w0 = bx << 7;
    const float* xf = x + ((size_t)b*CTOT + 4) * HWsz;

    // stage feats (zero-pad OOB rows/cols), fp32 -> bf16
    for (int i = tid; i < 3*64*130; i += 256) {
        int col = i % 130;
        int t   = i / 130;
        int ch  = t & 63;
        int r   = t >> 6;
        int gr = h - 1 + r;
        int gc = w0 - 1 + col;
        float v = 0.f;
        if (((unsigned)gr < (unsigned)H_) && ((unsigned)gc < (unsigned)W_))
            v = xf[(size_t)ch*HWsz + gr*W_ + gc];
        fe[r][col][ch] = f2bf(v);
    }
    // stage softmax weights
    for (int i = tid; i < 9*128; i += 256) {
        int k = i >> 7, px = i & 127;
        wl[k][px] = wbuf[((size_t)by*9 + k)*W_ + w0 + px];
    }
    __syncthreads();

    int lane = tid & 63, wv = tid >> 6;
    int q = lane >> 4, i15 = lane & 15;
    int pxb = wv * 32;

    const f32x4 fz = {0.f, 0.f, 0.f, 0.f};
    f32x4 fin[2][4], tmp[2][4];
#pragma unroll
    for (int m = 0; m < 2; ++m)
#pragma unroll
        for (int n = 0; n < 4; ++n) { fin[m][n] = fz; tmp[m][n] = fz; }

    for (int k9 = 0; k9 < 9; ++k9) {
        int r  = k9 / 3;          // fe row = 1 + dh
        int dw = k9 - r*3 - 1;

        // A fragments: A[row=i15][k=q*8+j] = feats(px, ch) direct from LDS
        s16x8 a[2][2];
#pragma unroll
        for (int m = 0; m < 2; ++m) {
            const unsigned short* ap = &fe[r][pxb + m*16 + i15 + 1 + dw][q*8];
            a[m][0] = *(const s16x8*)ap;          // ch 0..31 chunk
            a[m][1] = *(const s16x8*)(ap + 32);   // ch 32..63 chunk
        }
        // B fragments: B[k=q*8+j][n=i15] = Wagg[n][k9*64 + ch] (bf16, L2-resident)
        s16x8 bf[4][2];
        const unsigned short* bk = Bw + k9*64 + q*8;
#pragma unroll
        for (int n = 0; n < 4; ++n) {
            const unsigned short* bp = bk + (size_t)(n*16 + i15) * (9*CIN);
            bf[n][0] = *(const s16x8*)bp;
            bf[n][1] = *(const s16x8*)(bp + 32);
        }
#pragma unroll
        for (int m = 0; m < 2; ++m)
#pragma unroll
            for (int n = 0; n < 4; ++n) {
                tmp[m][n] = __builtin_amdgcn_mfma_f32_16x16x32_bf16(a[m][0], bf[n][0], tmp[m][n], 0, 0, 0);
                tmp[m][n] = __builtin_amdgcn_mfma_f32_16x16x32_bf16(a[m][1], bf[n][1], tmp[m][n], 0, 0, 0);
            }
        // post-scale by softmax weight (row-dependent only): fin += w_k(row) * tmp
#pragma unroll
        for (int m = 0; m < 2; ++m) {
            f32x4 ws = *(const f32x4*)&wl[k9][pxb + m*16 + q*4];
#pragma unroll
            for (int n = 0; n < 4; ++n) {
                fin[m][n] += ws * tmp[m][n];
                tmp[m][n] = fz;
            }
        }
    }

    // epilogue: BN2 + ReLU, store 4 consecutive w per lane (float4)
#pragma unroll
    for (int n = 0; n < 4; ++n) {
        int o = n*16 + i15;
        float sc = s2[o], tc = t2[o];
#pragma unroll
        for (int m = 0; m < 2; ++m) {
            f32x4 v = fin[m][n];
#pragma unroll
            for (int r2 = 0; r2 < 4; ++r2) v[r2] = fmaxf(fmaf(v[r2], sc, tc), 0.f);
            int wg = w0 + pxb + m*16 + q*4;
            float* dst = out + (((size_t)b*COUT + o)*H_ + h)*W_ + wg;
            *(f32x4*)dst = v;
        }
    }
}

extern "C" void kernel_launch(void* const* d_in, const int* in_sizes, int n_in,
                              void* d_out, int out_size, void* d_ws, size_t ws_size,
                              hipStream_t stream)
{
    const float* x    = (const float*)d_in[0];
    const int*   mask = (const int*)d_in[1];
    const float* W1   = (const float*)d_in[2];
    const float* g1   = (const float*)d_in[3];
    const float* b1   = (const float*)d_in[4];
    const float* m1   = (const float*)d_in[5];
    const float* v1   = (const float*)d_in[6];
    const float* W2   = (const float*)d_in[7];
    const float* b2   = (const float*)d_in[8];
    const float* Wagg = (const float*)d_in[9];
    const float* g2   = (const float*)d_in[10];
    const float* bb2  = (const float*)d_in[11];
    const float* m2   = (const float*)d_in[12];
    const float* v2   = (const float*)d_in[13];
    float* outp = (float*)d_out;

    char* ws = (char*)d_ws;
    float* W1s = (float*)(ws + 0);        // 256 f
    float* t1  = (float*)(ws + 1024);     // 64 f
    float* W2c = (float*)(ws + 1280);     // 64 f
    float* s2  = (float*)(ws + 1536);     // 64 f
    float* t2  = (float*)(ws + 1792);     // 64 f
    unsigned short* Bw = (unsigned short*)(ws + 4096);   // 36,864 bf16 = 73,728 B
    float* wbuf = (float*)(ws + 81920);   // 2*64*9*2048 f = 9.4 MB

    hipLaunchKernelGGL(prep_k, dim3(1), dim3(256), 0, stream,
                       W1, g1, b1, m1, v1, W2, Wagg, g2, bb2, m2, v2,
                       W1s, t1, W2c, s2, t2, Bw);
    hipLaunchKernelGGL(wsoft_k, dim3(1024), dim3(256), 0, stream,
                       x, mask, W1s, t1, W2c, b2, wbuf);
    hipLaunchKernelGGL(agg_k, dim3(16, 128), dim3(256), 0, stream,
                       x, Bw, wbuf, s2, t2, outp);
}

// Round 2
// 228.755 us; speedup vs baseline: 1.7760x; 1.7760x over previous
//
#include <hip/hip_runtime.h>

#define H_ 64
#define W_ 2048
#define HWsz (H_*W_)
#define CIN 64
#define CTOT 68
#define COUT 64

typedef float  f32x4  __attribute__((ext_vector_type(4)));
typedef float  f32x16 __attribute__((ext_vector_type(16)));
typedef short  s16x8  __attribute__((ext_vector_type(8)));

__device__ __forceinline__ unsigned short f2bf(float f) {
    unsigned u = __builtin_bit_cast(unsigned, f);
    unsigned r = u + 0x7fffu + ((u >> 16) & 1u);   // RNE; inputs finite
    return (unsigned short)(r >> 16);
}

// ---------------- prep: Wagg -> bf16 in exact MFMA B-fragment order ----------------
// BwS[((k9*4+ks)*2+nt)*512 + lane*8 + j] = Wagg[nt*32+(lane&31)][k9*64 + ks*16 + (lane>>5)*8 + j]
__global__ __launch_bounds__(256) void prep_bw(
    const float* __restrict__ Wagg, unsigned short* __restrict__ BwS)
{
    int idx = blockIdx.x * 256 + threadIdx.x;
    if (idx >= 4608) return;
    int lane = idx & 63;
    int rest = idx >> 6;          // 0..71
    int nt = rest & 1;
    int ks = (rest >> 1) & 3;
    int k9 = rest >> 3;           // 0..8
    int o  = nt*32 + (lane & 31);
    int ch = ks*16 + (lane >> 5)*8;
    const float* src = Wagg + (size_t)o*(9*CIN) + k9*64 + ch;
    s16x8 v8;
#pragma unroll
    for (int j = 0; j < 8; ++j) v8[j] = (short)f2bf(src[j]);
    *(s16x8*)(BwS + (size_t)idx*8) = v8;
}

// ---------------- logits + masked softmax -> 9 fp32 weights / pixel ----------------
__global__ __launch_bounds__(256, 4) void wsoft_k(
    const float* __restrict__ x, const int* __restrict__ mask,
    const float* __restrict__ W1, const float* __restrict__ g1,
    const float* __restrict__ b1, const float* __restrict__ m1,
    const float* __restrict__ v1, const float* __restrict__ W2,
    const float* __restrict__ b2p, float* __restrict__ wbuf)
{
    __shared__ float pos[3][4][260];
    __shared__ float musk[3][260];
    __shared__ float Wc[64][8];

    int tid = threadIdx.x;
    int bx = blockIdx.x, by = blockIdx.y;
    int b = by >> 6, h = by & 63;
    int w0 = bx << 8;
    const float* xb = x + (size_t)b * CTOT * HWsz;

    // pos interior: 3 iters, task=(r,ch,grp64); r,ch wave-uniform
#pragma unroll
    for (int it = 0; it < 3; ++it) {
        int i = it*256 + tid;
        int grp = i & 63;
        int rc = i >> 6;          // 0..11
        int ch = rc & 3, r = rc >> 2;
        int gr = h - 1 + r;
        float4 v = {0.f, 0.f, 0.f, 0.f};
        if ((unsigned)gr < (unsigned)H_)
            v = *(const float4*)(xb + (size_t)ch*HWsz + (size_t)gr*W_ + w0 + grp*4);
        float* dst = &pos[r][ch][1 + grp*4];
        dst[0] = v.x; dst[1] = v.y; dst[2] = v.z; dst[3] = v.w;
    }
    // mask interior
    if (tid < 192) {
        int grp = tid & 63, r = tid >> 6;
        int gr = h - 1 + r;
        float4 mv = {0.f, 0.f, 0.f, 0.f};
        if ((unsigned)gr < (unsigned)H_) {
            const int* mp = mask + ((size_t)b*H_ + gr)*W_ + w0 + grp*4;
            mv.x = (float)mp[0]; mv.y = (float)mp[1]; mv.z = (float)mp[2]; mv.w = (float)mp[3];
        }
        float* dst = &musk[r][1 + grp*4];
        dst[0] = mv.x; dst[1] = mv.y; dst[2] = mv.z; dst[3] = mv.w;
    }
    // halos
    if (tid < 24) {
        int c2 = tid & 1;
        int rc = tid >> 1; int ch = rc & 3, r = rc >> 2;
        int gr = h - 1 + r, gc = w0 - 1 + c2*257;
        float v = 0.f;
        if (((unsigned)gr < (unsigned)H_) && ((unsigned)gc < (unsigned)W_))
            v = xb[(size_t)ch*HWsz + (size_t)gr*W_ + gc];
        pos[r][ch][c2*257] = v;
    }
    if (tid >= 32 && tid < 38) {
        int t = tid - 32;
        int c2 = t & 1, r = t >> 1;
        int gr = h - 1 + r, gc = w0 - 1 + c2*257;
        float v = 0.f;
        if (((unsigned)gr < (unsigned)H_) && ((unsigned)gc < (unsigned)W_))
            v = (float)mask[((size_t)b*H_ + gr)*W_ + gc];
        musk[r][c2*257] = v;
    }
    // folded BN1 constants
    if (tid >= 64 && tid < 128) {
        int c = tid - 64;
        float s1 = g1[c] * rsqrtf(v1[c] + 1e-5f);
#pragma unroll
        for (int m = 0; m < 4; ++m) Wc[c][m] = W1[c*4 + m] * s1;
        Wc[c][4] = b1[c] - m1[c]*s1;
        Wc[c][5] = W2[c];
    }
    __syncthreads();

    int px = tid;
    float pc[4];
#pragma unroll
    for (int m = 0; m < 4; ++m) pc[m] = pos[1][m][1 + px];
    float d[9][4], mu[9];
#pragma unroll
    for (int k = 0; k < 9; ++k) {
        int r = k/3, dw = k%3 - 1;
#pragma unroll
        for (int m = 0; m < 4; ++m) d[k][m] = pos[r][m][1 + px + dw] - pc[m];
        mu[k] = musk[r][1 + px + dw];
    }

    float lg[9];
#pragma unroll
    for (int k = 0; k < 9; ++k) lg[k] = 0.f;

#pragma unroll 4
    for (int c = 0; c < CIN; ++c) {
        f32x4 wv = *(const f32x4*)&Wc[c][0];
        float t1c = Wc[c][4], w2c = Wc[c][5];
#pragma unroll
        for (int k = 0; k < 9; ++k) {
            float v = fmaf(d[k][0], wv[0], fmaf(d[k][1], wv[1],
                      fmaf(d[k][2], wv[2], fmaf(d[k][3], wv[3], t1c))));
            lg[k] += fmaxf(v, 0.f) * w2c;
        }
    }

    float b2v = b2p[0];
    float mx = -1e30f;
#pragma unroll
    for (int k = 0; k < 9; ++k) { lg[k] = (lg[k] + b2v) * mu[k]; mx = fmaxf(mx, lg[k]); }
    float s = 0.f, e[9];
#pragma unroll
    for (int k = 0; k < 9; ++k) { e[k] = __expf(lg[k] - mx); s += e[k]; }
    float inv = 1.f / s;
#pragma unroll
    for (int k = 0; k < 9; ++k)
        wbuf[((size_t)by*9 + k)*W_ + w0 + px] = e[k] * inv;
}

// ---------------- MFMA aggregation (32x32x16 bf16) ----------------
// Block: 256 thr (4 waves), tile = 64 px (one row) x 64 outputs.
// Wave (nt, mq): outputs nt*32..+31, pixels mq*32..+31.
// LDS feats: fe[r][granule][col][8ch] -> both staging writes and A-frag
// reads are contiguous-16B-per-lane (conflict-free), 25.3 KB total.
__global__ __launch_bounds__(256, 4) void agg_k(
    const float* __restrict__ x,
    const unsigned short* __restrict__ BwS,
    const float* __restrict__ wbuf,
    const float* __restrict__ g2, const float* __restrict__ bb2,
    const float* __restrict__ m2, const float* __restrict__ v2,
    float* __restrict__ out)
{
    __shared__ __align__(16) unsigned short fe[3][8][66][8];

    int tid = threadIdx.x;
    int bx = blockIdx.x, by = blockIdx.y;
    int b = by >> 6, h = by & 63;
    int w0 = bx << 6;
    const float* xf = x + ((size_t)b*CTOT + 4) * HWsz;

    // interior staging: task = (r, g, col64); r,g wave-uniform
#pragma unroll
    for (int it = 0; it < 6; ++it) {
        int i = it*256 + tid;
        int col = i & 63;
        int rg = i >> 6;            // 0..23
        int g = rg & 7, r = rg >> 3;
        int gr = h - 1 + r;
        s16x8 v8 = {0,0,0,0,0,0,0,0};
        if ((unsigned)gr < (unsigned)H_) {
            const float* src = xf + (size_t)(g*8)*HWsz + (size_t)gr*W_ + w0 + col;
#pragma unroll
            for (int j = 0; j < 8; ++j) v8[j] = (short)f2bf(src[(size_t)j*HWsz]);
        }
        *(s16x8*)&fe[r][g][1 + col][0] = v8;
    }
    // halo staging: 48 tasks (2 cols x 3r x 8g)
    if (tid < 48) {
        int c2 = tid & 1;
        int rg = tid >> 1;
        int g = rg & 7, r = rg >> 3;
        int gr = h - 1 + r;
        int gc = w0 - 1 + c2*65;
        s16x8 v8 = {0,0,0,0,0,0,0,0};
        if (((unsigned)gr < (unsigned)H_) && ((unsigned)gc < (unsigned)W_)) {
            const float* src = xf + (size_t)(g*8)*HWsz + (size_t)gr*W_ + gc;
#pragma unroll
            for (int j = 0; j < 8; ++j) v8[j] = (short)f2bf(src[(size_t)j*HWsz]);
        }
        *(s16x8*)&fe[r][g][c2*65][0] = v8;
    }
    __syncthreads();

    int lane = tid & 63, wv = tid >> 6;
    int nt = wv & 1, mq = wv >> 1;
    int l31 = lane & 31, l5 = lane >> 5;

    f32x16 fin = {0.f,0.f,0.f,0.f,0.f,0.f,0.f,0.f,0.f,0.f,0.f,0.f,0.f,0.f,0.f,0.f};
    const float* wrow = wbuf + (size_t)by*9*W_ + w0 + mq*32 + 4*l5;

#pragma unroll
    for (int k9 = 0; k9 < 9; ++k9) {
        const int r = k9/3, dw = k9%3 - 1;
        int col = 1 + mq*32 + l31 + dw;

        s16x8 bf[4], af[4];
#pragma unroll
        for (int ks = 0; ks < 4; ++ks)
            bf[ks] = *(const s16x8*)(BwS + (size_t)((((k9<<2) + ks)*2 + nt) << 9) + lane*8);
#pragma unroll
        for (int ks = 0; ks < 4; ++ks)
            af[ks] = *(const s16x8*)&fe[r][ks*2 + l5][col][0];

        f32x16 tmp = {0.f,0.f,0.f,0.f,0.f,0.f,0.f,0.f,0.f,0.f,0.f,0.f,0.f,0.f,0.f,0.f};
#pragma unroll
        for (int ks = 0; ks < 4; ++ks)
            tmp = __builtin_amdgcn_mfma_f32_32x32x16_bf16(af[ks], bf[ks], tmp, 0, 0, 0);

        // softmax-weight scale: row(reg=4v+c) = 8v + c + 4*l5
        const float* wk = wrow + (size_t)k9*W_;
        f32x4 a0 = *(const f32x4*)(wk);
        f32x4 a1 = *(const f32x4*)(wk + 8);
        f32x4 a2 = *(const f32x4*)(wk + 16);
        f32x4 a3 = *(const f32x4*)(wk + 24);
#pragma unroll
        for (int c = 0; c < 4; ++c) {
            fin[c]      += a0[c] * tmp[c];
            fin[4 + c]  += a1[c] * tmp[4 + c];
            fin[8 + c]  += a2[c] * tmp[8 + c];
            fin[12 + c] += a3[c] * tmp[12 + c];
        }
    }

    // epilogue: BN2 + ReLU
    int o = nt*32 + l31;
    float sc = g2[o] * rsqrtf(v2[o] + 1e-5f);
    float tc = bb2[o] - m2[o]*sc;
    float* orow = out + (((size_t)b*COUT + o)*H_ + h)*W_ + w0 + mq*32 + 4*l5;
#pragma unroll
    for (int v = 0; v < 4; ++v) {
        f32x4 q;
#pragma unroll
        for (int c = 0; c < 4; ++c) q[c] = fmaxf(fmaf(fin[4*v + c], sc, tc), 0.f);
        *(f32x4*)(orow + 8*v) = q;
    }
}

extern "C" void kernel_launch(void* const* d_in, const int* in_sizes, int n_in,
                              void* d_out, int out_size, void* d_ws, size_t ws_size,
                              hipStream_t stream)
{
    const float* x    = (const float*)d_in[0];
    const int*   mask = (const int*)d_in[1];
    const float* W1   = (const float*)d_in[2];
    const float* g1   = (const float*)d_in[3];
    const float* b1   = (const float*)d_in[4];
    const float* m1   = (const float*)d_in[5];
    const float* v1   = (const float*)d_in[6];
    const float* W2   = (const float*)d_in[7];
    const float* b2   = (const float*)d_in[8];
    const float* Wagg = (const float*)d_in[9];
    const float* g2   = (const float*)d_in[10];
    const float* bb2  = (const float*)d_in[11];
    const float* m2   = (const float*)d_in[12];
    const float* v2   = (const float*)d_in[13];
    float* outp = (float*)d_out;

    char* ws = (char*)d_ws;
    unsigned short* BwS = (unsigned short*)(ws + 0);        // 36,864 bf16 = 73,728 B
    float* wbuf = (float*)(ws + 131072);                    // 2*64*9*2048 f = 9.4 MB

    hipLaunchKernelGGL(prep_bw, dim3(18), dim3(256), 0, stream, Wagg, BwS);
    hipLaunchKernelGGL(wsoft_k, dim3(W_/256, 128), dim3(256), 0, stream,
                       x, mask, W1, g1, b1, m1, v1, W2, b2, wbuf);
    hipLaunchKernelGGL(agg_k, dim3(W_/64, 128), dim3(256), 0, stream,
                       x, BwS, wbuf, g2, bb2, m2, v2, outp);
}

// Round 3
// 217.755 us; speedup vs baseline: 1.8658x; 1.0505x over previous
//
#include <hip/hip_runtime.h>

#define H_ 64
#define W_ 2048
#define HWsz (H_*W_)
#define CIN 64
#define CTOT 68
#define COUT 64

// padded bf16 feats layout: [b][hr 0..65][g 0..7][wc 0..2049][8ch]
#define XH 66
#define XW 2050

typedef float  f32x4  __attribute__((ext_vector_type(4)));
typedef float  f32x16 __attribute__((ext_vector_type(16)));
typedef short  s16x8  __attribute__((ext_vector_type(8)));

__device__ __forceinline__ unsigned short f2bf(float f) {
    unsigned u = __builtin_bit_cast(unsigned, f);
    unsigned r = u + 0x7fffu + ((u >> 16) & 1u);   // RNE; inputs finite
    return (unsigned short)(r >> 16);
}

// ---------------- prep: Wagg -> bf16 in exact MFMA B-fragment order ----------------
__global__ __launch_bounds__(256) void prep_bw(
    const float* __restrict__ Wagg, unsigned short* __restrict__ BwS)
{
    int idx = blockIdx.x * 256 + threadIdx.x;
    if (idx >= 4608) return;
    int lane = idx & 63;
    int rest = idx >> 6;          // 0..71
    int nt = rest & 1;
    int ks = (rest >> 1) & 3;
    int k9 = rest >> 3;           // 0..8
    int o  = nt*32 + (lane & 31);
    int ch = ks*16 + (lane >> 5)*8;
    const float* src = Wagg + (size_t)o*(9*CIN) + k9*64 + ch;
    s16x8 v8;
#pragma unroll
    for (int j = 0; j < 8; ++j) v8[j] = (short)f2bf(src[j]);
    *(s16x8*)(BwS + (size_t)idx*8) = v8;
}

// ---------------- prep: feats -> zero-padded bf16 granule layout ----------------
__global__ __launch_bounds__(256) void prep_x(
    const float* __restrict__ x, unsigned short* __restrict__ xpad)
{
    int wc = blockIdx.x * 256 + threadIdx.x;
    if (wc >= XW) return;
    int hr = blockIdx.y;
    int b  = blockIdx.z;
    bool interior = (hr >= 1) && (hr <= H_) && (wc >= 1) && (wc <= W_);
    const float* src0 = x + ((size_t)b*CTOT + 4)*HWsz + (size_t)(hr-1)*W_ + (wc-1);
    unsigned short* dst0 = xpad + ((((size_t)b*XH + hr)*8)*XW + wc)*8;
#pragma unroll
    for (int g = 0; g < 8; ++g) {
        s16x8 v8 = {0,0,0,0,0,0,0,0};
        if (interior) {
            const float* s = src0 + (size_t)(g*8)*HWsz;
#pragma unroll
            for (int j = 0; j < 8; ++j) v8[j] = (short)f2bf(s[(size_t)j*HWsz]);
        }
        *(s16x8*)(dst0 + (size_t)g*XW*8) = v8;
    }
}

// ---------------- logits + masked softmax -> 9 fp32 weights / pixel ----------------
__global__ __launch_bounds__(256, 4) void wsoft_k(
    const float* __restrict__ x, const int* __restrict__ mask,
    const float* __restrict__ W1, const float* __restrict__ g1,
    const float* __restrict__ b1, const float* __restrict__ m1,
    const float* __restrict__ v1, const float* __restrict__ W2,
    const float* __restrict__ b2p, float* __restrict__ wbuf)
{
    __shared__ float pos[3][4][260];
    __shared__ float musk[3][260];
    __shared__ float Wc[64][8];

    int tid = threadIdx.x;
    int bx = blockIdx.x, by = blockIdx.y;
    int b = by >> 6, h = by & 63;
    int w0 = bx << 8;
    const float* xb = x + (size_t)b * CTOT * HWsz;

#pragma unroll
    for (int it = 0; it < 3; ++it) {
        int i = it*256 + tid;
        int grp = i & 63;
        int rc = i >> 6;
        int ch = rc & 3, r = rc >> 2;
        int gr = h - 1 + r;
        float4 v = {0.f, 0.f, 0.f, 0.f};
        if ((unsigned)gr < (unsigned)H_)
            v = *(const float4*)(xb + (size_t)ch*HWsz + (size_t)gr*W_ + w0 + grp*4);
        float* dst = &pos[r][ch][1 + grp*4];
        dst[0] = v.x; dst[1] = v.y; dst[2] = v.z; dst[3] = v.w;
    }
    if (tid < 192) {
        int grp = tid & 63, r = tid >> 6;
        int gr = h - 1 + r;
        float4 mv = {0.f, 0.f, 0.f, 0.f};
        if ((unsigned)gr < (unsigned)H_) {
            const int* mp = mask + ((size_t)b*H_ + gr)*W_ + w0 + grp*4;
            mv.x = (float)mp[0]; mv.y = (float)mp[1]; mv.z = (float)mp[2]; mv.w = (float)mp[3];
        }
        float* dst = &musk[r][1 + grp*4];
        dst[0] = mv.x; dst[1] = mv.y; dst[2] = mv.z; dst[3] = mv.w;
    }
    if (tid < 24) {
        int c2 = tid & 1;
        int rc = tid >> 1; int ch = rc & 3, r = rc >> 2;
        int gr = h - 1 + r, gc = w0 - 1 + c2*257;
        float v = 0.f;
        if (((unsigned)gr < (unsigned)H_) && ((unsigned)gc < (unsigned)W_))
            v = xb[(size_t)ch*HWsz + (size_t)gr*W_ + gc];
        pos[r][ch][c2*257] = v;
    }
    if (tid >= 32 && tid < 38) {
        int t = tid - 32;
        int c2 = t & 1, r = t >> 1;
        int gr = h - 1 + r, gc = w0 - 1 + c2*257;
        float v = 0.f;
        if (((unsigned)gr < (unsigned)H_) && ((unsigned)gc < (unsigned)W_))
            v = (float)mask[((size_t)b*H_ + gr)*W_ + gc];
        musk[r][c2*257] = v;
    }
    if (tid >= 64 && tid < 128) {
        int c = tid - 64;
        float s1 = g1[c] * rsqrtf(v1[c] + 1e-5f);
#pragma unroll
        for (int m = 0; m < 4; ++m) Wc[c][m] = W1[c*4 + m] * s1;
        float t1c = b1[c] - m1[c]*s1;
        float w2c = W2[c];
        Wc[c][4] = t1c;
        Wc[c][5] = w2c;
        Wc[c][6] = fmaxf(t1c, 0.f) * w2c;   // center-tap (d==0) contribution
        Wc[c][7] = 0.f;
    }
    __syncthreads();

    int px = tid;
    float pc[4];
#pragma unroll
    for (int m = 0; m < 4; ++m) pc[m] = pos[1][m][1 + px];
    float d[9][4], mu[9];
#pragma unroll
    for (int k = 0; k < 9; ++k) {
        int r = k/3, dw = k%3 - 1;
#pragma unroll
        for (int m = 0; m < 4; ++m) d[k][m] = pos[r][m][1 + px + dw] - pc[m];
        mu[k] = musk[r][1 + px + dw];
    }

    float lg[9];
#pragma unroll
    for (int k = 0; k < 9; ++k) lg[k] = 0.f;
    float lg4 = 0.f;

#pragma unroll 4
    for (int c = 0; c < CIN; ++c) {
        f32x4 wv = *(const f32x4*)&Wc[c][0];
        f32x4 w2 = *(const f32x4*)&Wc[c][4];
        lg4 += w2[2];
#pragma unroll
        for (int kk = 0; kk < 8; ++kk) {
            const int k = kk + (kk >= 4);     // skip center
            float v = fmaf(d[k][0], wv[0], fmaf(d[k][1], wv[1],
                      fmaf(d[k][2], wv[2], fmaf(d[k][3], wv[3], w2[0]))));
            lg[k] += fmaxf(v, 0.f) * w2[1];
        }
    }
    lg[4] = lg4;

    float b2v = b2p[0];
    float mx = -1e30f;
#pragma unroll
    for (int k = 0; k < 9; ++k) { lg[k] = (lg[k] + b2v) * mu[k]; mx = fmaxf(mx, lg[k]); }
    float s = 0.f, e[9];
#pragma unroll
    for (int k = 0; k < 9; ++k) { e[k] = __expf(lg[k] - mx); s += e[k]; }
    float inv = 1.f / s;
#pragma unroll
    for (int k = 0; k < 9; ++k)
        wbuf[((size_t)by*9 + k)*W_ + w0 + px] = e[k] * inv;
}

// ---------------- MFMA aggregation v2: bf16 prepacked + global_load_lds ----------------
// Block: 256 thr (4 waves), tile = 128 px (one row) x 64 outputs.
// Wave (nt = wv&1, mh = wv>>1): outputs nt*32..+31, pixels mh*64..+63 (2 m-tiles).
__global__ __launch_bounds__(256, 3) void agg_k2(
    const unsigned short* __restrict__ xpad,
    const unsigned short* __restrict__ BwS,
    const float* __restrict__ wbuf,
    const float* __restrict__ g2, const float* __restrict__ bb2,
    const float* __restrict__ m2, const float* __restrict__ v2,
    float* __restrict__ out)
{
    __shared__ __align__(16) unsigned short fe[3][8][130][8];   // 49,920 B

    int tid = threadIdx.x;
    int bx = blockIdx.x, by = blockIdx.y;
    int b = by >> 6, h = by & 63;
    int w0 = bx << 7;                       // 128-px tile
    int lane = tid & 63, wv = tid >> 6;

    const unsigned short* xb = xpad + (size_t)b*XH*8*XW*8;

    // interior staging: 48 chunks of 64 granules, direct global->LDS (16B/lane)
#pragma unroll
    for (int it = 0; it < 12; ++it) {
        int u = it*4 + wv;                  // wave-uniform
        int chunk = u & 1, g = (u >> 1) & 7, r = u >> 4;
        const unsigned short* gsrc =
            xb + ((((size_t)(h + r)*8 + g)*XW) + w0 + 1 + chunk*64 + lane)*8;
        unsigned short* ldst = &fe[r][g][1 + chunk*64][0];
        __builtin_amdgcn_global_load_lds(
            (const __attribute__((address_space(1))) unsigned int*)gsrc,
            (__attribute__((address_space(3))) unsigned int*)ldst, 16, 0, 0);
    }
    // halo: cols j=0 and j=129 (always valid thanks to padding)
    if (tid < 48) {
        int c2 = tid & 1, g = (tid >> 1) & 7, r = tid >> 4;
        int wc = w0 + c2*129;
        s16x8 v8 = *(const s16x8*)(xb + ((((size_t)(h + r)*8 + g)*XW) + wc)*8);
        *(s16x8*)&fe[r][g][c2*129][0] = v8;
    }
    __syncthreads();

    int nt = wv & 1, mh = wv >> 1;
    int l31 = lane & 31, l5 = lane >> 5;

    const f32x16 fz16 = {0.f,0.f,0.f,0.f,0.f,0.f,0.f,0.f,0.f,0.f,0.f,0.f,0.f,0.f,0.f,0.f};
    f32x16 fin[2] = {fz16, fz16};
    const float* wrow = wbuf + (size_t)by*9*W_ + w0 + mh*64 + 4*l5;

#pragma unroll
    for (int k9 = 0; k9 < 9; ++k9) {
        const int r = k9/3, dw = k9%3 - 1;

        s16x8 bf[4];
#pragma unroll
        for (int ks = 0; ks < 4; ++ks)
            bf[ks] = *(const s16x8*)(BwS + (size_t)((((k9<<2) + ks)*2 + nt) << 9) + lane*8);

        const float* wk = wrow + (size_t)k9*W_;
#pragma unroll
        for (int half = 0; half < 2; ++half) {
            int j0 = 1 + mh*64 + half*32 + l31 + dw;
            f32x16 tmp = fz16;
#pragma unroll
            for (int ks = 0; ks < 4; ++ks) {
                s16x8 af = *(const s16x8*)&fe[r][ks*2 + l5][j0][0];
                tmp = __builtin_amdgcn_mfma_f32_32x32x16_bf16(af, bf[ks], tmp, 0, 0, 0);
            }
            f32x4 a0 = *(const f32x4*)(wk + half*32);
            f32x4 a1 = *(const f32x4*)(wk + half*32 + 8);
            f32x4 a2 = *(const f32x4*)(wk + half*32 + 16);
            f32x4 a3 = *(const f32x4*)(wk + half*32 + 24);
#pragma unroll
            for (int c = 0; c < 4; ++c) {
                fin[half][c]      += a0[c] * tmp[c];
                fin[half][4 + c]  += a1[c] * tmp[4 + c];
                fin[half][8 + c]  += a2[c] * tmp[8 + c];
                fin[half][12 + c] += a3[c] * tmp[12 + c];
            }
        }
    }

    // epilogue: BN2 + ReLU
    int o = nt*32 + l31;
    float sc = g2[o] * rsqrtf(v2[o] + 1e-5f);
    float tc = bb2[o] - m2[o]*sc;
#pragma unroll
    for (int half = 0; half < 2; ++half) {
        float* orow = out + (((size_t)b*COUT + o)*H_ + h)*W_ + w0 + mh*64 + half*32 + 4*l5;
#pragma unroll
        for (int v = 0; v < 4; ++v) {
            f32x4 q;
#pragma unroll
            for (int c = 0; c < 4; ++c) q[c] = fmaxf(fmaf(fin[half][4*v + c], sc, tc), 0.f);
            *(f32x4*)(orow + 8*v) = q;
        }
    }
}

// ---------------- fallback aggregation (R2 path, used if ws too small) ----------------
__global__ __launch_bounds__(256, 4) void agg_k(
    const float* __restrict__ x,
    const unsigned short* __restrict__ BwS,
    const float* __restrict__ wbuf,
    const float* __restrict__ g2, const float* __restrict__ bb2,
    const float* __restrict__ m2, const float* __restrict__ v2,
    float* __restrict__ out)
{
    __shared__ __align__(16) unsigned short fe[3][8][66][8];

    int tid = threadIdx.x;
    int bx = blockIdx.x, by = blockIdx.y;
    int b = by >> 6, h = by & 63;
    int w0 = bx << 6;
    const float* xf = x + ((size_t)b*CTOT + 4) * HWsz;

#pragma unroll
    for (int it = 0; it < 6; ++it) {
        int i = it*256 + tid;
        int col = i & 63;
        int rg = i >> 6;
        int g = rg & 7, r = rg >> 3;
        int gr = h - 1 + r;
        s16x8 v8 = {0,0,0,0,0,0,0,0};
        if ((unsigned)gr < (unsigned)H_) {
            const float* src = xf + (size_t)(g*8)*HWsz + (size_t)gr*W_ + w0 + col;
#pragma unroll
            for (int j = 0; j < 8; ++j) v8[j] = (short)f2bf(src[(size_t)j*HWsz]);
        }
        *(s16x8*)&fe[r][g][1 + col][0] = v8;
    }
    if (tid < 48) {
        int c2 = tid & 1;
        int rg = tid >> 1;
        int g = rg & 7, r = rg >> 3;
        int gr = h - 1 + r;
        int gc = w0 - 1 + c2*65;
        s16x8 v8 = {0,0,0,0,0,0,0,0};
        if (((unsigned)gr < (unsigned)H_) && ((unsigned)gc < (unsigned)W_)) {
            const float* src = xf + (size_t)(g*8)*HWsz + (size_t)gr*W_ + gc;
#pragma unroll
            for (int j = 0; j < 8; ++j) v8[j] = (short)f2bf(src[(size_t)j*HWsz]);
        }
        *(s16x8*)&fe[r][g][c2*65][0] = v8;
    }
    __syncthreads();

    int lane = tid & 63, wv = tid >> 6;
    int nt = wv & 1, mq = wv >> 1;
    int l31 = lane & 31, l5 = lane >> 5;

    f32x16 fin = {0.f,0.f,0.f,0.f,0.f,0.f,0.f,0.f,0.f,0.f,0.f,0.f,0.f,0.f,0.f,0.f};
    const float* wrow = wbuf + (size_t)by*9*W_ + w0 + mq*32 + 4*l5;

#pragma unroll
    for (int k9 = 0; k9 < 9; ++k9) {
        const int r = k9/3, dw = k9%3 - 1;
        int col = 1 + mq*32 + l31 + dw;

        s16x8 bf[4], af[4];
#pragma unroll
        for (int ks = 0; ks < 4; ++ks)
            bf[ks] = *(const s16x8*)(BwS + (size_t)((((k9<<2) + ks)*2 + nt) << 9) + lane*8);
#pragma unroll
        for (int ks = 0; ks < 4; ++ks)
            af[ks] = *(const s16x8*)&fe[r][ks*2 + l5][col][0];

        f32x16 tmp = {0.f,0.f,0.f,0.f,0.f,0.f,0.f,0.f,0.f,0.f,0.f,0.f,0.f,0.f,0.f,0.f};
#pragma unroll
        for (int ks = 0; ks < 4; ++ks)
            tmp = __builtin_amdgcn_mfma_f32_32x32x16_bf16(af[ks], bf[ks], tmp, 0, 0, 0);

        const float* wk = wrow + (size_t)k9*W_;
        f32x4 a0 = *(const f32x4*)(wk);
        f32x4 a1 = *(const f32x4*)(wk + 8);
        f32x4 a2 = *(const f32x4*)(wk + 16);
        f32x4 a3 = *(const f32x4*)(wk + 24);
#pragma unroll
        for (int c = 0; c < 4; ++c) {
            fin[c]      += a0[c] * tmp[c];
            fin[4 + c]  += a1[c] * tmp[4 + c];
            fin[8 + c]  += a2[c] * tmp[8 + c];
            fin[12 + c] += a3[c] * tmp[12 + c];
        }
    }

    int o = nt*32 + l31;
    float sc = g2[o] * rsqrtf(v2[o] + 1e-5f);
    float tc = bb2[o] - m2[o]*sc;
    float* orow = out + (((size_t)b*COUT + o)*H_ + h)*W_ + w0 + mq*32 + 4*l5;
#pragma unroll
    for (int v = 0; v < 4; ++v) {
        f32x4 q;
#pragma unroll
        for (int c = 0; c < 4; ++c) q[c] = fmaxf(fmaf(fin[4*v + c], sc, tc), 0.f);
        *(f32x4*)(orow + 8*v) = q;
    }
}

extern "C" void kernel_launch(void* const* d_in, const int* in_sizes, int n_in,
                              void* d_out, int out_size, void* d_ws, size_t ws_size,
                              hipStream_t stream)
{
    const float* x    = (const float*)d_in[0];
    const int*   mask = (const int*)d_in[1];
    const float* W1   = (const float*)d_in[2];
    const float* g1   = (const float*)d_in[3];
    const float* b1   = (const float*)d_in[4];
    const float* m1   = (const float*)d_in[5];
    const float* v1   = (const float*)d_in[6];
    const float* W2   = (const float*)d_in[7];
    const float* b2   = (const float*)d_in[8];
    const float* Wagg = (const float*)d_in[9];
    const float* g2   = (const float*)d_in[10];
    const float* bb2  = (const float*)d_in[11];
    const float* m2   = (const float*)d_in[12];
    const float* v2   = (const float*)d_in[13];
    float* outp = (float*)d_out;

    char* ws = (char*)d_ws;
    const size_t xpadBytes = (size_t)2*XH*8*XW*8*2;        // 34,636,800
    const size_t bwOff  = 34637824;                        // aligned past xpad
    const size_t wbOff  = bwOff + 131072;
    const size_t need   = wbOff + (size_t)2*64*9*W_*4;     // ~44.2 MB
    (void)xpadBytes;

    if (ws_size >= need) {
        unsigned short* xpad = (unsigned short*)(ws + 0);
        unsigned short* BwS  = (unsigned short*)(ws + bwOff);
        float*          wbuf = (float*)(ws + wbOff);
        hipLaunchKernelGGL(prep_bw, dim3(18), dim3(256), 0, stream, Wagg, BwS);
        hipLaunchKernelGGL(prep_x, dim3((XW + 255)/256, XH, 2), dim3(256), 0, stream, x, xpad);
        hipLaunchKernelGGL(wsoft_k, dim3(W_/256, 128), dim3(256), 0, stream,
                           x, mask, W1, g1, b1, m1, v1, W2, b2, wbuf);
        hipLaunchKernelGGL(agg_k2, dim3(W_/128, 128), dim3(256), 0, stream,
                           xpad, BwS, wbuf, g2, bb2, m2, v2, outp);
    } else {
        unsigned short* BwS  = (unsigned short*)(ws + 0);
        float*          wbuf = (float*)(ws + 131072);
        hipLaunchKernelGGL(prep_bw, dim3(18), dim3(256), 0, stream, Wagg, BwS);
        hipLaunchKernelGGL(wsoft_k, dim3(W_/256, 128), dim3(256), 0, stream,
                           x, mask, W1, g1, b1, m1, v1, W2, b2, wbuf);
        hipLaunchKernelGGL(agg_k, dim3(W_/64, 128), dim3(256), 0, stream,
                           x, BwS, wbuf, g2, bb2, m2, v2, outp);
    }
}

// Round 4
// 207.271 us; speedup vs baseline: 1.9601x; 1.0506x over previous
//
#include <hip/hip_runtime.h>

#define H_ 64
#define W_ 2048
#define HWsz (H_*W_)
#define CIN 64
#define CTOT 68
#define COUT 64

// padded bf16 feats layout: [b][hr 0..65][g 0..7][wc 0..2049][8ch]
#define XH 66
#define XW 2050

typedef float  f32x4  __attribute__((ext_vector_type(4)));
typedef float  f32x16 __attribute__((ext_vector_type(16)));
typedef short  s16x8  __attribute__((ext_vector_type(8)));

__device__ __forceinline__ unsigned short f2bf(float f) {
    unsigned u = __builtin_bit_cast(unsigned, f);
    unsigned r = u + 0x7fffu + ((u >> 16) & 1u);   // RNE; inputs finite
    return (unsigned short)(r >> 16);
}

// ---------------- prep: Wagg -> bf16 B-fragments; fold BN1 into Wfold ----------------
// Wfold[c*8 + {0..3}] = W1[c][m]*s1(c); [4]=t1(c); [5]=W2[c]; Wfold[512] = sum_c relu(t1)*w2
__global__ __launch_bounds__(256) void prep_bw(
    const float* __restrict__ Wagg,
    const float* __restrict__ W1, const float* __restrict__ g1,
    const float* __restrict__ b1, const float* __restrict__ m1,
    const float* __restrict__ v1, const float* __restrict__ W2,
    unsigned short* __restrict__ BwS, float* __restrict__ Wfold)
{
    int tid = threadIdx.x;
    if (blockIdx.x == 0) {
        if (tid < 64) {
            float s1 = g1[tid] * rsqrtf(v1[tid] + 1e-5f);
#pragma unroll
            for (int m = 0; m < 4; ++m) Wfold[tid*8 + m] = W1[tid*4 + m] * s1;
            Wfold[tid*8 + 4] = b1[tid] - m1[tid]*s1;
            Wfold[tid*8 + 5] = W2[tid];
            Wfold[tid*8 + 6] = 0.f;
            Wfold[tid*8 + 7] = 0.f;
        }
        __syncthreads();
        if (tid == 0) {
            float s = 0.f;
            for (int c = 0; c < 64; ++c) s += fmaxf(Wfold[c*8 + 4], 0.f) * Wfold[c*8 + 5];
            Wfold[512] = s;
        }
    }
    int idx = blockIdx.x * 256 + tid;
    if (idx < 4608) {
        int lane = idx & 63;
        int rest = idx >> 6;
        int nt = rest & 1;
        int ks = (rest >> 1) & 3;
        int k9 = rest >> 3;
        int o  = nt*32 + (lane & 31);
        int ch = ks*16 + (lane >> 5)*8;
        const float* src = Wagg + (size_t)o*(9*CIN) + k9*64 + ch;
        s16x8 v8;
#pragma unroll
        for (int j = 0; j < 8; ++j) v8[j] = (short)f2bf(src[j]);
        *(s16x8*)(BwS + (size_t)idx*8) = v8;
    }
}

// ---------------- prep: feats -> bf16 granule pad; pos/mask -> fp32 pad ----------------
__global__ __launch_bounds__(256) void prep_xpm(
    const float* __restrict__ x, const int* __restrict__ mask,
    unsigned short* __restrict__ xpad,
    float* __restrict__ pospad, float* __restrict__ maskpad)
{
    int wc = blockIdx.x * 256 + threadIdx.x;
    if (wc >= XW) return;
    int hr = blockIdx.y;
    int b  = blockIdx.z;
    bool interior = (hr >= 1) && (hr <= H_) && (wc >= 1) && (wc <= W_);
    const float* srcf = x + ((size_t)b*CTOT + 4)*HWsz + (size_t)(hr-1)*W_ + (wc-1);
    unsigned short* dst0 = xpad + ((((size_t)b*XH + hr)*8)*XW + wc)*8;
#pragma unroll
    for (int g = 0; g < 8; ++g) {
        s16x8 v8 = {0,0,0,0,0,0,0,0};
        if (interior) {
            const float* s = srcf + (size_t)(g*8)*HWsz;
#pragma unroll
            for (int j = 0; j < 8; ++j) v8[j] = (short)f2bf(s[(size_t)j*HWsz]);
        }
        *(s16x8*)(dst0 + (size_t)g*XW*8) = v8;
    }
    const float* srcp = x + (size_t)b*CTOT*HWsz + (size_t)(hr-1)*W_ + (wc-1);
#pragma unroll
    for (int ch = 0; ch < 4; ++ch) {
        float v = interior ? srcp[(size_t)ch*HWsz] : 0.f;
        pospad[(((size_t)b*XH + hr)*4 + ch)*XW + wc] = v;
    }
    float mv = interior ? (float)mask[((size_t)b*H_ + (hr-1))*W_ + (wc-1)] : 0.f;
    maskpad[((size_t)b*XH + hr)*XW + wc] = mv;
}

// ---------------- fused: logits + softmax + MFMA aggregation ----------------
// Block: 256 thr (4 waves), tile = 1 row x 128 px x 64 outputs.
// Phase A: issue feats DMA; compute logits (2 thr/px, 4 taps each, k-split;
//          waves 0-1: taps {0,1,2,3}, waves 2-3: taps {5,6,7,8}).
// Phase B: softmax in LDS sw[9][128]. Phase C: MFMA (as agg_k2, weights from LDS).
__global__ __launch_bounds__(256, 2) void fused_k(
    const unsigned short* __restrict__ xpad,
    const float* __restrict__ pospad, const float* __restrict__ maskpad,
    const unsigned short* __restrict__ BwS, const float* __restrict__ Wfold,
    const float* __restrict__ b2p,
    const float* __restrict__ g2, const float* __restrict__ bb2,
    const float* __restrict__ m2, const float* __restrict__ v2,
    float* __restrict__ out)
{
    __shared__ __align__(16) unsigned short fe[3][8][130][8];   // 49,920 B
    __shared__ __align__(16) float sw[9][128];                  //  4,608 B

    int tid = threadIdx.x;
    int bx = blockIdx.x, by = blockIdx.y;
    int b = by >> 6, h = by & 63;
    int w0 = bx << 7;
    int lane = tid & 63, wv = tid >> 6;

    const unsigned short* xb = xpad + (size_t)b*XH*8*XW*8;

    // --- issue feats DMA: 48 chunks (12 per wave), global->LDS 16B/lane ---
#pragma unroll
    for (int it = 0; it < 12; ++it) {
        int u = it*4 + wv;
        int chunk = u & 1, g = (u >> 1) & 7, r = u >> 4;
        const unsigned short* gsrc =
            xb + ((((size_t)(h + r)*8 + g)*XW) + w0 + 1 + chunk*64 + lane)*8;
        unsigned short* ldst = &fe[r][g][1 + chunk*64][0];
        __builtin_amdgcn_global_load_lds(
            (const __attribute__((address_space(1))) unsigned int*)gsrc,
            (__attribute__((address_space(3))) unsigned int*)ldst, 16, 0, 0);
    }
    // --- halo granules into regs (write to LDS later, before barrier) ---
    s16x8 haloV = {0,0,0,0,0,0,0,0};
    int hg = 0, hr3 = 0, hc2 = 0;
    if (tid < 48) {
        hc2 = tid & 1; hg = (tid >> 1) & 7; hr3 = tid >> 4;
        haloV = *(const s16x8*)(xb + ((((size_t)(h + hr3)*8 + hg)*XW) + w0 + hc2*129)*8);
    }

    // --- Phase A: logits (k-split) ---
    int px = tid & 127, kh = tid >> 7;            // kh wave-uniform
    int gw = w0 + px;
    float pA[4][3], pB[4], pc[4], mu[4];
    {
        int rowA = h + (kh ? 2 : 0);
#pragma unroll
        for (int ch = 0; ch < 4; ++ch) {
            const float* pr = pospad + (((size_t)b*XH + rowA)*4 + ch)*XW + gw;
            pA[ch][0] = pr[0]; pA[ch][1] = pr[1]; pA[ch][2] = pr[2];
            const float* p1 = pospad + (((size_t)b*XH + h + 1)*4 + ch)*XW + gw;
            pB[ch] = p1[2*kh];
            pc[ch] = p1[1];
        }
        const float* mr0 = maskpad + ((size_t)b*XH + rowA)*XW + gw;
        const float* mr1 = maskpad + ((size_t)b*XH + h + 1)*XW + gw;
        if (kh == 0) {
            mu[0] = mr0[0]; mu[1] = mr0[1]; mu[2] = mr0[2]; mu[3] = mr1[0];
        } else {
            mu[0] = mr1[2]; mu[1] = mr0[0]; mu[2] = mr0[1]; mu[3] = mr0[2];
        }
    }
    float dd[4][4];
#pragma unroll
    for (int m = 0; m < 4; ++m) {
        if (kh == 0) {
            dd[0][m] = pA[m][0] - pc[m]; dd[1][m] = pA[m][1] - pc[m];
            dd[2][m] = pA[m][2] - pc[m]; dd[3][m] = pB[m]    - pc[m];
        } else {
            dd[0][m] = pB[m]    - pc[m]; dd[1][m] = pA[m][0] - pc[m];
            dd[2][m] = pA[m][1] - pc[m]; dd[3][m] = pA[m][2] - pc[m];
        }
    }

    float lg[4] = {0.f, 0.f, 0.f, 0.f};
    const f32x4* Wf4 = (const f32x4*)Wfold;
#pragma unroll 8
    for (int c = 0; c < CIN; ++c) {
        f32x4 wa = Wf4[2*c];        // W1s[0..3] — wave-uniform s_load
        f32x4 wb = Wf4[2*c + 1];    // t1, w2
#pragma unroll
        for (int t = 0; t < 4; ++t) {
            float v = fmaf(dd[t][0], wa[0], fmaf(dd[t][1], wa[1],
                      fmaf(dd[t][2], wa[2], fmaf(dd[t][3], wa[3], wb[0]))));
            lg[t] += fmaxf(v, 0.f) * wb[1];
        }
    }
    float b2v = b2p[0];
#pragma unroll
    for (int t = 0; t < 4; ++t) {
        int k = kh ? (5 + t) : t;
        sw[k][px] = (lg[t] + b2v) * mu[t];
    }
    if (tid < 48) *(s16x8*)&fe[hr3][hg][hc2*129][0] = haloV;
    __syncthreads();   // drains feats DMA + halo + sw logit writes

    // --- Phase B: softmax (128 threads, each owns one pixel column) ---
    if (tid < 128) {
        int p2 = tid, g2w = w0 + p2;
        float mu4 = maskpad[((size_t)b*XH + h + 1)*XW + g2w + 1];
        float lgv[9];
#pragma unroll
        for (int k = 0; k < 9; ++k) if (k != 4) lgv[k] = sw[k][p2];
        lgv[4] = (Wfold[512] + b2v) * mu4;
        float mx = -1e30f;
#pragma unroll
        for (int k = 0; k < 9; ++k) mx = fmaxf(mx, lgv[k]);
        float s = 0.f, e[9];
#pragma unroll
        for (int k = 0; k < 9; ++k) { e[k] = __expf(lgv[k] - mx); s += e[k]; }
        float inv = 1.f / s;
#pragma unroll
        for (int k = 0; k < 9; ++k) sw[k][p2] = e[k] * inv;
    }
    __syncthreads();

    // --- Phase C: MFMA aggregation (32x32x16 bf16) ---
    int nt = wv & 1, mh = wv >> 1;
    int l31 = lane & 31, l5 = lane >> 5;

    const f32x16 fz16 = {0.f,0.f,0.f,0.f,0.f,0.f,0.f,0.f,0.f,0.f,0.f,0.f,0.f,0.f,0.f,0.f};
    f32x16 fin[2] = {fz16, fz16};

#pragma unroll
    for (int k9 = 0; k9 < 9; ++k9) {
        const int r = k9/3, dw = k9%3 - 1;

        s16x8 bf[4];
#pragma unroll
        for (int ks = 0; ks < 4; ++ks)
            bf[ks] = *(const s16x8*)(BwS + (size_t)((((k9<<2) + ks)*2 + nt) << 9) + lane*8);

#pragma unroll
        for (int half = 0; half < 2; ++half) {
            int j0 = 1 + mh*64 + half*32 + l31 + dw;
            f32x16 tmp = fz16;
#pragma unroll
            for (int ks = 0; ks < 4; ++ks) {
                s16x8 af = *(const s16x8*)&fe[r][ks*2 + l5][j0][0];
                tmp = __builtin_amdgcn_mfma_f32_32x32x16_bf16(af, bf[ks], tmp, 0, 0, 0);
            }
            int wbase = mh*64 + half*32 + 4*l5;
            f32x4 a0 = *(const f32x4*)&sw[k9][wbase];
            f32x4 a1 = *(const f32x4*)&sw[k9][wbase + 8];
            f32x4 a2 = *(const f32x4*)&sw[k9][wbase + 16];
            f32x4 a3 = *(const f32x4*)&sw[k9][wbase + 24];
#pragma unroll
            for (int c = 0; c < 4; ++c) {
                fin[half][c]      += a0[c] * tmp[c];
                fin[half][4 + c]  += a1[c] * tmp[4 + c];
                fin[half][8 + c]  += a2[c] * tmp[8 + c];
                fin[half][12 + c] += a3[c] * tmp[12 + c];
            }
        }
    }

    // --- epilogue: BN2 + ReLU ---
    int o = nt*32 + l31;
    float sc = g2[o] * rsqrtf(v2[o] + 1e-5f);
    float tc = bb2[o] - m2[o]*sc;
#pragma unroll
    for (int half = 0; half < 2; ++half) {
        float* orow = out + (((size_t)b*COUT + o)*H_ + h)*W_ + w0 + mh*64 + half*32 + 4*l5;
#pragma unroll
        for (int v = 0; v < 4; ++v) {
            f32x4 q;
#pragma unroll
            for (int c = 0; c < 4; ++c) q[c] = fmaxf(fmaf(fin[half][4*v + c], sc, tc), 0.f);
            *(f32x4*)(orow + 8*v) = q;
        }
    }
}

extern "C" void kernel_launch(void* const* d_in, const int* in_sizes, int n_in,
                              void* d_out, int out_size, void* d_ws, size_t ws_size,
                              hipStream_t stream)
{
    const float* x    = (const float*)d_in[0];
    const int*   mask = (const int*)d_in[1];
    const float* W1   = (const float*)d_in[2];
    const float* g1   = (const float*)d_in[3];
    const float* b1   = (const float*)d_in[4];
    const float* m1   = (const float*)d_in[5];
    const float* v1   = (const float*)d_in[6];
    const float* W2   = (const float*)d_in[7];
    const float* b2   = (const float*)d_in[8];
    const float* Wagg = (const float*)d_in[9];
    const float* g2   = (const float*)d_in[10];
    const float* bb2  = (const float*)d_in[11];
    const float* m2   = (const float*)d_in[12];
    const float* v2   = (const float*)d_in[13];
    float* outp = (float*)d_out;

    char* ws = (char*)d_ws;
    // layout (all 16B aligned):
    unsigned short* xpad    = (unsigned short*)(ws + 0);           // 34,636,800 B
    float*          pospad  = (float*)(ws + 34636800);             //  4,329,600 B
    float*          maskpad = (float*)(ws + 38966400);             //  1,082,400 B
    unsigned short* BwS     = (unsigned short*)(ws + 40048800);    //     73,728 B
    float*          Wfold   = (float*)(ws + 40122528);             //      2,052 B

    hipLaunchKernelGGL(prep_bw, dim3(18), dim3(256), 0, stream,
                       Wagg, W1, g1, b1, m1, v1, W2, BwS, Wfold);
    hipLaunchKernelGGL(prep_xpm, dim3((XW + 255)/256, XH, 2), dim3(256), 0, stream,
                       x, mask, xpad, pospad, maskpad);
    hipLaunchKernelGGL(fused_k, dim3(W_/128, 128), dim3(256), 0, stream,
                       xpad, pospad, maskpad, BwS, Wfold, b2,
                       g2, bb2, m2, v2, outp);
}

// Round 5
// 202.425 us; speedup vs baseline: 2.0071x; 1.0239x over previous
//
#include <hip/hip_runtime.h>

#define H_ 64
#define W_ 2048
#define HWsz (H_*W_)
#define CIN 64
#define CTOT 68
#define COUT 64

// padded bf16 feats layout: [b][hr 0..65][g 0..7][wc 0..2049][8ch]
#define XH 66
#define XW 2050

typedef float  f32x4  __attribute__((ext_vector_type(4)));
typedef float  f32x16 __attribute__((ext_vector_type(16)));
typedef short  s16x8  __attribute__((ext_vector_type(8)));

__device__ __forceinline__ unsigned short f2bf(float f) {
    unsigned u = __builtin_bit_cast(unsigned, f);
    unsigned r = u + 0x7fffu + ((u >> 16) & 1u);   // RNE; inputs finite
    return (unsigned short)(r >> 16);
}

// ---------------- prep: Wagg -> bf16 fragments (A-operand layout); fold BN1 ----------------
// BwS idx lane l: o = nt*32+(l&31), ch = ks*16+(l>>5)*8+j  == MFMA A[m=o][k=ch] layout
__global__ __launch_bounds__(256) void prep_bw(
    const float* __restrict__ Wagg,
    const float* __restrict__ W1, const float* __restrict__ g1,
    const float* __restrict__ b1, const float* __restrict__ m1,
    const float* __restrict__ v1, const float* __restrict__ W2,
    unsigned short* __restrict__ BwS, float* __restrict__ Wfold)
{
    int tid = threadIdx.x;
    if (blockIdx.x == 0) {
        if (tid < 64) {
            float s1 = g1[tid] * rsqrtf(v1[tid] + 1e-5f);
#pragma unroll
            for (int m = 0; m < 4; ++m) Wfold[tid*8 + m] = W1[tid*4 + m] * s1;
            Wfold[tid*8 + 4] = b1[tid] - m1[tid]*s1;
            Wfold[tid*8 + 5] = W2[tid];
            Wfold[tid*8 + 6] = 0.f;
            Wfold[tid*8 + 7] = 0.f;
        }
        __syncthreads();
        if (tid == 0) {
            float s = 0.f;
            for (int c = 0; c < 64; ++c) s += fmaxf(Wfold[c*8 + 4], 0.f) * Wfold[c*8 + 5];
            Wfold[512] = s;
        }
    }
    int idx = blockIdx.x * 256 + tid;
    if (idx < 4608) {
        int lane = idx & 63;
        int rest = idx >> 6;
        int nt = rest & 1;
        int ks = (rest >> 1) & 3;
        int k9 = rest >> 3;
        int o  = nt*32 + (lane & 31);
        int ch = ks*16 + (lane >> 5)*8;
        const float* src = Wagg + (size_t)o*(9*CIN) + k9*64 + ch;
        s16x8 v8;
#pragma unroll
        for (int j = 0; j < 8; ++j) v8[j] = (short)f2bf(src[j]);
        *(s16x8*)(BwS + (size_t)idx*8) = v8;
    }
}

// ---------------- prep: feats -> bf16 granule pad; pos/mask -> fp32 pad ----------------
__global__ __launch_bounds__(256) void prep_xpm(
    const float* __restrict__ x, const int* __restrict__ mask,
    unsigned short* __restrict__ xpad,
    float* __restrict__ pospad, float* __restrict__ maskpad)
{
    int wc = blockIdx.x * 256 + threadIdx.x;
    if (wc >= XW) return;
    int hr = blockIdx.y;
    int b  = blockIdx.z;
    bool interior = (hr >= 1) && (hr <= H_) && (wc >= 1) && (wc <= W_);
    const float* srcf = x + ((size_t)b*CTOT + 4)*HWsz + (size_t)(hr-1)*W_ + (wc-1);
    unsigned short* dst0 = xpad + ((((size_t)b*XH + hr)*8)*XW + wc)*8;
#pragma unroll
    for (int g = 0; g < 8; ++g) {
        s16x8 v8 = {0,0,0,0,0,0,0,0};
        if (interior) {
            const float* s = srcf + (size_t)(g*8)*HWsz;
#pragma unroll
            for (int j = 0; j < 8; ++j) v8[j] = (short)f2bf(s[(size_t)j*HWsz]);
        }
        *(s16x8*)(dst0 + (size_t)g*XW*8) = v8;
    }
    const float* srcp = x + (size_t)b*CTOT*HWsz + (size_t)(hr-1)*W_ + (wc-1);
#pragma unroll
    for (int ch = 0; ch < 4; ++ch) {
        float v = interior ? srcp[(size_t)ch*HWsz] : 0.f;
        pospad[(((size_t)b*XH + hr)*4 + ch)*XW + wc] = v;
    }
    float mv = interior ? (float)mask[((size_t)b*H_ + (hr-1))*W_ + (wc-1)] : 0.f;
    maskpad[((size_t)b*XH + hr)*XW + wc] = mv;
}

// ---------------- fused: logits + softmax + MFMA aggregation (A/B swapped) ----------------
// Block: 256 thr (4 waves), tile = 1 row x 64 px x 64 outputs. 5 blocks/CU.
// Phase A: feats DMA in flight; logits (grp=wave handles 2 taps x 64 px).
// Phase B: softmax (tid<64). Phase C: MFMA with A=Wagg, B=feats ->
// C[col=lane&31]=px -> coalesced dword stores (128B segments).
__global__ __launch_bounds__(256, 5) void fused_k(
    const unsigned short* __restrict__ xpad,
    const float* __restrict__ pospad, const float* __restrict__ maskpad,
    const unsigned short* __restrict__ BwS, const float* __restrict__ Wfold,
    const float* __restrict__ b2p,
    const float* __restrict__ g2, const float* __restrict__ bb2,
    const float* __restrict__ m2, const float* __restrict__ v2,
    float* __restrict__ out)
{
    __shared__ __align__(16) unsigned short fe[3][8][66][8];   // 25,344 B
    __shared__ __align__(16) float sw[9][64];                  //  2,304 B
    __shared__ __align__(16) float sbn[2][64];                 //    512 B

    int tid = threadIdx.x;
    int bx = blockIdx.x, by = blockIdx.y;
    int b = by >> 6, h = by & 63;
    int w0 = bx << 6;
    int lane = tid & 63, wv = tid >> 6;

    const unsigned short* xb = xpad + (size_t)b*XH*8*XW*8;

    // --- feats DMA: 24 chunks (6 per wave), global->LDS 16B/lane ---
#pragma unroll
    for (int it = 0; it < 6; ++it) {
        int u = it*4 + wv;                  // wave-uniform
        int g = u & 7, r = u >> 3;
        const unsigned short* gsrc = xb + ((((size_t)(h + r)*8 + g)*XW) + w0 + 1 + lane)*8;
        unsigned short* ldst = &fe[r][g][1][0];
        __builtin_amdgcn_global_load_lds(
            (const __attribute__((address_space(1))) unsigned int*)gsrc,
            (__attribute__((address_space(3))) unsigned int*)ldst, 16, 0, 0);
    }
    // --- halo granules into regs ---
    s16x8 haloV = {0,0,0,0,0,0,0,0};
    int hg = 0, hr3 = 0, hc2 = 0;
    if (tid < 48) {
        hc2 = tid & 1; hg = (tid >> 1) & 7; hr3 = tid >> 4;
        haloV = *(const s16x8*)(xb + ((((size_t)(h + hr3)*8 + hg)*XW) + w0 + hc2*65)*8);
    }
    // --- BN2 table ---
    if (tid >= 192) {
        int o = tid - 192;
        float sc = g2[o] * rsqrtf(v2[o] + 1e-5f);
        sbn[0][o] = sc;
        sbn[1][o] = bb2[o] - m2[o]*sc;
    }

    // --- Phase A: logits. grp (=wave) handles taps {k0,k0+1}, px = tid&63 ---
    int px = tid & 63, grp = wv;
    int k0 = 2*grp + (grp >> 1);            // 0,2,5,7
    int k1 = k0 + 1;
    const float* pb = pospad + (size_t)b*XH*4*XW;
    const float* mb = maskpad + (size_t)b*XH*XW;
    int gw = w0 + px;

    float pc[4], dd[2][4], mu[2];
#pragma unroll
    for (int ch = 0; ch < 4; ++ch)
        pc[ch] = pb[((size_t)(h+1)*4 + ch)*XW + gw + 1];
    {
        int r0 = k0/3, d0 = k0%3, r1 = k1/3, d1 = k1%3;
#pragma unroll
        for (int ch = 0; ch < 4; ++ch) {
            dd[0][ch] = pb[((size_t)(h+r0)*4 + ch)*XW + gw + d0] - pc[ch];
            dd[1][ch] = pb[((size_t)(h+r1)*4 + ch)*XW + gw + d1] - pc[ch];
        }
        mu[0] = mb[(size_t)(h+r0)*XW + gw + d0];
        mu[1] = mb[(size_t)(h+r1)*XW + gw + d1];
    }

    float lg[2] = {0.f, 0.f};
    const f32x4* Wf4 = (const f32x4*)Wfold;
#pragma unroll 8
    for (int c = 0; c < CIN; ++c) {
        f32x4 wa = Wf4[2*c];
        f32x4 wb = Wf4[2*c + 1];
#pragma unroll
        for (int t = 0; t < 2; ++t) {
            float v = fmaf(dd[t][0], wa[0], fmaf(dd[t][1], wa[1],
                      fmaf(dd[t][2], wa[2], fmaf(dd[t][3], wa[3], wb[0]))));
            lg[t] += fmaxf(v, 0.f) * wb[1];
        }
    }
    float b2v = b2p[0];
    sw[k0][px] = (lg[0] + b2v) * mu[0];
    sw[k1][px] = (lg[1] + b2v) * mu[1];
    if (tid < 48) *(s16x8*)&fe[hr3][hg][hc2*65][0] = haloV;
    __syncthreads();   // drains feats DMA + halo + logit writes

    // --- Phase B: softmax (tid<64, one pixel each) ---
    if (tid < 64) {
        float mu4 = mb[(size_t)(h+1)*XW + w0 + tid + 1];
        float lgv[9];
#pragma unroll
        for (int k = 0; k < 9; ++k) if (k != 4) lgv[k] = sw[k][tid];
        lgv[4] = (Wfold[512] + b2v) * mu4;
        float mx = -1e30f;
#pragma unroll
        for (int k = 0; k < 9; ++k) mx = fmaxf(mx, lgv[k]);
        float s = 0.f, e[9];
#pragma unroll
        for (int k = 0; k < 9; ++k) { e[k] = __expf(lgv[k] - mx); s += e[k]; }
        float inv = 1.f / s;
#pragma unroll
        for (int k = 0; k < 9; ++k) sw[k][tid] = e[k] * inv;
    }
    __syncthreads();

    // --- Phase C: MFMA, A=Wagg (m=o), B=feats (n=px) ---
    int nt = wv & 1, mh = wv >> 1;          // o-tile, px-tile
    int l31 = lane & 31, l5 = lane >> 5;

    const f32x16 fz16 = {0.f,0.f,0.f,0.f,0.f,0.f,0.f,0.f,0.f,0.f,0.f,0.f,0.f,0.f,0.f,0.f};
    f32x16 fin = fz16;

#pragma unroll
    for (int k9 = 0; k9 < 9; ++k9) {
        const int r = k9/3, dwp = k9%3;
        int col = mh*32 + l31 + dwp;        // fe col for px + (dwp-1), incl. +1 pad

        s16x8 aw[4];
#pragma unroll
        for (int ks = 0; ks < 4; ++ks)
            aw[ks] = *(const s16x8*)(BwS + (size_t)((((k9<<2) + ks)*2 + nt) << 9) + lane*8);

        f32x16 tmp = fz16;
#pragma unroll
        for (int ks = 0; ks < 4; ++ks) {
            s16x8 bfr = *(const s16x8*)&fe[r][ks*2 + l5][col][0];
            tmp = __builtin_amdgcn_mfma_f32_32x32x16_bf16(aw[ks], bfr, tmp, 0, 0, 0);
        }
        float wsc = sw[k9][mh*32 + l31];    // per-lane scalar (px-dependent)
#pragma unroll
        for (int c = 0; c < 16; ++c) fin[c] += wsc * tmp[c];
    }

    // --- epilogue: BN2 + ReLU, coalesced dword stores ---
    int obase = nt*32 + 4*l5;
    float* od = out + (((size_t)b*COUT + obase)*H_ + h)*W_ + w0 + mh*32 + l31;
#pragma unroll
    for (int v = 0; v < 4; ++v) {
        f32x4 sc4 = *(const f32x4*)&sbn[0][obase + 8*v];
        f32x4 tc4 = *(const f32x4*)&sbn[1][obase + 8*v];
#pragma unroll
        for (int c = 0; c < 4; ++c) {
            float val = fmaxf(fmaf(fin[4*v + c], sc4[c], tc4[c]), 0.f);
            od[(size_t)(8*v + c)*HWsz] = val;
        }
    }
}

extern "C" void kernel_launch(void* const* d_in, const int* in_sizes, int n_in,
                              void* d_out, int out_size, void* d_ws, size_t ws_size,
                              hipStream_t stream)
{
    const float* x    = (const float*)d_in[0];
    const int*   mask = (const int*)d_in[1];
    const float* W1   = (const float*)d_in[2];
    const float* g1   = (const float*)d_in[3];
    const float* b1   = (const float*)d_in[4];
    const float* m1   = (const float*)d_in[5];
    const float* v1   = (const float*)d_in[6];
    const float* W2   = (const float*)d_in[7];
    const float* b2   = (const float*)d_in[8];
    const float* Wagg = (const float*)d_in[9];
    const float* g2   = (const float*)d_in[10];
    const float* bb2  = (const float*)d_in[11];
    const float* m2   = (const float*)d_in[12];
    const float* v2   = (const float*)d_in[13];
    float* outp = (float*)d_out;

    char* ws = (char*)d_ws;
    unsigned short* xpad    = (unsigned short*)(ws + 0);           // 34,636,800 B
    float*          pospad  = (float*)(ws + 34636800);             //  4,329,600 B
    float*          maskpad = (float*)(ws + 38966400);             //  1,082,400 B
    unsigned short* BwS     = (unsigned short*)(ws + 40048800);    //     73,728 B
    float*          Wfold   = (float*)(ws + 40122528);             //      2,052 B

    hipLaunchKernelGGL(prep_bw, dim3(18), dim3(256), 0, stream,
                       Wagg, W1, g1, b1, m1, v1, W2, BwS, Wfold);
    hipLaunchKernelGGL(prep_xpm, dim3((XW + 255)/256, XH, 2), dim3(256), 0, stream,
                       x, mask, xpad, pospad, maskpad);
    hipLaunchKernelGGL(fused_k, dim3(W_/64, 128), dim3(256), 0, stream,
                       xpad, pospad, maskpad, BwS, Wfold, b2,
                       g2, bb2, m2, v2, outp);
}

// Round 7
// 186.055 us; speedup vs baseline: 2.1837x; 1.0880x over previous
//
#include <hip/hip_runtime.h>
#include <hip/hip_bf16.h>

#define H_ 64
#define W_ 2048
#define HWsz (H_*W_)
#define CIN 64
#define CTOT 68
#define COUT 64

typedef float  f32x2  __attribute__((ext_vector_type(2)));
typedef float  f32x4  __attribute__((ext_vector_type(4)));
typedef float  f32x16 __attribute__((ext_vector_type(16)));
typedef short  s16x8  __attribute__((ext_vector_type(8)));

__device__ __forceinline__ unsigned short f2bf(float f) {
    unsigned u = __builtin_bit_cast(unsigned, f);
    unsigned r = u + 0x7fffu + ((u >> 16) & 1u);   // RNE; inputs finite
    return (unsigned short)(r >> 16);
}

__device__ __forceinline__ unsigned pack2bf(float a, float b) {
    __hip_bfloat162 h = __float22bfloat162_rn(float2{a, b});   // v_cvt_pk_bf16_f32
    unsigned u;
    __builtin_memcpy(&u, &h, 4);
    return u;
}

// ---------------- prep: Wagg -> bf16 MFMA A-fragments; fold BN1 ----------------
// BwS idx lane l: o = nt*32+(l&31), ch = ks*16+(l>>5)*8+j  (A[m=o][k=ch] layout)
__global__ __launch_bounds__(256) void prep_bw(
    const float* __restrict__ Wagg,
    const float* __restrict__ W1, const float* __restrict__ g1,
    const float* __restrict__ b1, const float* __restrict__ m1,
    const float* __restrict__ v1, const float* __restrict__ W2,
    unsigned short* __restrict__ BwS, float* __restrict__ Wfold)
{
    int tid = threadIdx.x;
    if (blockIdx.x == 0) {
        if (tid < 64) {
            float s1 = g1[tid] * rsqrtf(v1[tid] + 1e-5f);
#pragma unroll
            for (int m = 0; m < 4; ++m) Wfold[tid*8 + m] = W1[tid*4 + m] * s1;
            Wfold[tid*8 + 4] = b1[tid] - m1[tid]*s1;
            Wfold[tid*8 + 5] = W2[tid];
            Wfold[tid*8 + 6] = 0.f;
            Wfold[tid*8 + 7] = 0.f;
        }
        __syncthreads();
        if (tid == 0) {
            float s = 0.f;
            for (int c = 0; c < 64; ++c) s += fmaxf(Wfold[c*8 + 4], 0.f) * Wfold[c*8 + 5];
            Wfold[512] = s;
        }
    }
    int idx = blockIdx.x * 256 + tid;
    if (idx < 4608) {
        int lane = idx & 63;
        int rest = idx >> 6;
        int nt = rest & 1;
        int ks = (rest >> 1) & 3;
        int k9 = rest >> 3;
        int o  = nt*32 + (lane & 31);
        int ch = ks*16 + (lane >> 5)*8;
        const float* src = Wagg + (size_t)o*(9*CIN) + k9*64 + ch;
        s16x8 v8;
#pragma unroll
        for (int j = 0; j < 8; ++j) v8[j] = (short)f2bf(src[j]);
        *(s16x8*)(BwS + (size_t)idx*8) = v8;
    }
}

// tap geometry + pos/mask loads for 4 taps starting at compile-time base KB
// (KB=0 -> taps 0..3, KB=5 -> taps 5..8); dd2[p][ch] packs taps {2p,2p+1}
template<int KB>
__device__ __forceinline__ void tap_load(
    const float* __restrict__ xp, const int* __restrict__ mk,
    int h, int gw, const float pc[4], f32x2 dd2[2][4], f32x2 mu2[2])
{
#pragma unroll
    for (int i = 0; i < 4; ++i) {
        const int k = KB + i;                    // compile-time after unroll
        const int r = k/3 - 1, d = k%3 - 1;
        int ih = h + r, iw = gw + d;
        bool ok = ((unsigned)ih < (unsigned)H_) && ((unsigned)iw < (unsigned)W_);
        int ihc = min(max(ih, 0), H_-1);
        int iwc = min(max(iw, 0), W_-1);
        float m = ok ? (float)mk[(size_t)ihc*W_ + iwc] : 0.f;
        mu2[i>>1][i&1] = m;
#pragma unroll
        for (int ch = 0; ch < 4; ++ch) {
            float p = xp[(size_t)ch*HWsz + (size_t)ihc*W_ + iwc];
            p = ok ? p : 0.f;                    // reference zero-pads pn
            dd2[i>>1][ch][i&1] = p - pc[ch];
        }
    }
}

// ---------------- mega: stage + logits + softmax + MFMA + epilogue ----------------
// Block: 256 thr (4 waves), tile = 2 rows x 64 px x 64 outputs. 4 blocks/CU.
// Phase A: stage feats fp32->bf16 into LDS; logits (wave=(row,tapgroup), 4 taps/thr, packed f32x2).
// Phase B: softmax (tid<128). Phase C: MFMA A=Wagg B=feats, wave=(nt,row); coalesced stores.
__global__ __launch_bounds__(256, 4) void mega_k(
    const float* __restrict__ x, const int* __restrict__ mask,
    const unsigned short* __restrict__ BwS, const float* __restrict__ Wfold,
    const float* __restrict__ b2p,
    const float* __restrict__ g2, const float* __restrict__ bb2,
    const float* __restrict__ m2, const float* __restrict__ v2,
    float* __restrict__ out)
{
    __shared__ __align__(16) unsigned short fe[4][8][66][8];   // 33,792 B
    __shared__ __align__(16) float sw[2][9][64];               //  4,608 B
    __shared__ __align__(16) float sbn[2][64];                 //    512 B

    const int tid = threadIdx.x;
    const int bx = blockIdx.x, by = blockIdx.y;
    const int b = by >> 5, h0 = (by & 31) << 1;
    const int w0 = bx << 6;
    const int lane = tid & 63, wv = tid >> 6;

    const float* xf = x + ((size_t)b*CTOT + 4)*HWsz;   // feat channels
    const float* xp = x + (size_t)b*CTOT*HWsz;         // pos channels 0..3
    const int*   mk = mask + (size_t)b*HWsz;

    // BN2 table
    if (tid >= 192) {
        int o = tid - 192;
        float sc = g2[o] * rsqrtf(v2[o] + 1e-5f);
        sbn[0][o] = sc;
        sbn[1][o] = bb2[o] - m2[o]*sc;
    }

    // --- staging: interior, 32 (r,g) granule-chunks, 8 per wave, lane=col ---
#pragma unroll
    for (int it = 0; it < 8; ++it) {
        int u = it*4 + wv;                  // wave-uniform
        int g = u & 7, r = u >> 3;
        int gr = h0 - 1 + r;
        uint4 q = {0u, 0u, 0u, 0u};
        if ((unsigned)gr < (unsigned)H_) {
            const float* src = xf + (size_t)(g*8)*HWsz + (size_t)gr*W_ + w0 + lane;
            float v[8];
#pragma unroll
            for (int j = 0; j < 8; ++j) v[j] = src[(size_t)j*HWsz];
            q.x = pack2bf(v[0], v[1]); q.y = pack2bf(v[2], v[3]);
            q.z = pack2bf(v[4], v[5]); q.w = pack2bf(v[6], v[7]);
        }
        *(uint4*)&fe[r][g][1 + lane][0] = q;
    }
    // --- halo: 64 tasks (2 cols x 4 r x 8 g) ---
    if (tid < 64) {
        int c2 = tid & 1, g = (tid >> 1) & 7, r = tid >> 4;
        int gr = h0 - 1 + r, gc = w0 - 1 + c2*65;
        uint4 q = {0u, 0u, 0u, 0u};
        if (((unsigned)gr < (unsigned)H_) && ((unsigned)gc < (unsigned)W_)) {
            const float* src = xf + (size_t)(g*8)*HWsz + (size_t)gr*W_ + gc;
            float v[8];
#pragma unroll
            for (int j = 0; j < 8; ++j) v[j] = src[(size_t)j*HWsz];
            q.x = pack2bf(v[0], v[1]); q.y = pack2bf(v[2], v[3]);
            q.z = pack2bf(v[4], v[5]); q.w = pack2bf(v[6], v[7]);
        }
        *(uint4*)&fe[r][g][c2*65][0] = q;
    }

    // --- Phase A: logits. wave = (rowq = wv>>1, tg = wv&1), 4 taps/thread ---
    const int px = tid & 63, gw = w0 + px;
    const int rowq = wv >> 1, tg = wv & 1;
    const int h = h0 + rowq;

    float pc[4];
#pragma unroll
    for (int ch = 0; ch < 4; ++ch) pc[ch] = xp[(size_t)ch*HWsz + (size_t)h*W_ + gw];

    f32x2 dd2[2][4]; f32x2 mu2[2];
    if (tg == 0) tap_load<0>(xp, mk, h, gw, pc, dd2, mu2);
    else         tap_load<5>(xp, mk, h, gw, pc, dd2, mu2);

    const f32x4* Wf4 = (const f32x4*)Wfold;
    const f32x2 z2 = {0.f, 0.f};
    f32x2 lg2[2] = {z2, z2};
#pragma unroll 8
    for (int c = 0; c < CIN; ++c) {
        f32x4 wa = Wf4[2*c];        // wave-uniform s_load
        f32x4 wb = Wf4[2*c + 1];
#pragma unroll
        for (int p = 0; p < 2; ++p) {
            f32x2 v = {wb[0], wb[0]};
            v = dd2[p][0]*wa[0] + v;          // v_pk_fma_f32
            v = dd2[p][1]*wa[1] + v;
            v = dd2[p][2]*wa[2] + v;
            v = dd2[p][3]*wa[3] + v;
            v = __builtin_elementwise_max(v, z2);
            lg2[p] = v*wb[1] + lg2[p];
        }
    }
    float b2v = b2p[0];
#pragma unroll
    for (int i = 0; i < 4; ++i) {
        int k = i + 5*tg;                    // tg0 -> 0..3, tg1 -> 5..8
        sw[rowq][k][px] = (lg2[i>>1][i&1] + b2v) * mu2[i>>1][i&1];
    }
    __syncthreads();

    // --- Phase B: softmax (128 threads: row x px) ---
    if (tid < 128) {
        int rq = tid >> 6, p2 = tid & 63;
        float mu4 = (float)mk[(size_t)(h0 + rq)*W_ + w0 + p2];
        float lgv[9];
#pragma unroll
        for (int k = 0; k < 9; ++k) if (k != 4) lgv[k] = sw[rq][k][p2];
        lgv[4] = (Wfold[512] + b2v) * mu4;
        float mx = -1e30f;
#pragma unroll
        for (int k = 0; k < 9; ++k) mx = fmaxf(mx, lgv[k]);
        float s = 0.f, e[9];
#pragma unroll
        for (int k = 0; k < 9; ++k) { e[k] = __expf(lgv[k] - mx); s += e[k]; }
        float inv = 1.f / s;
#pragma unroll
        for (int k = 0; k < 9; ++k) sw[rq][k][p2] = e[k] * inv;
    }
    __syncthreads();

    // --- Phase C: MFMA. wave = (nt = wv&1, rh = wv>>1); A=Wagg, B=feats ---
    const int nt = wv & 1, rh = wv >> 1;
    const int l31 = lane & 31, l5 = lane >> 5;
    const int hC = h0 + rh;

    const f32x16 fz16 = {0.f,0.f,0.f,0.f,0.f,0.f,0.f,0.f,0.f,0.f,0.f,0.f,0.f,0.f,0.f,0.f};
    f32x16 fin[2] = {fz16, fz16};

#pragma unroll
    for (int k9 = 0; k9 < 9; ++k9) {
        const int rr = rh + k9/3;            // fe row (fe[0] = global row h0-1)
        const int dwp = k9 % 3;

        s16x8 aw[4];
#pragma unroll
        for (int ks = 0; ks < 4; ++ks)
            aw[ks] = *(const s16x8*)(BwS + (size_t)((((k9<<2) + ks)*2 + nt) << 9) + lane*8);

#pragma unroll
        for (int half = 0; half < 2; ++half) {
            int col = half*32 + l31 + dwp;   // 1 + px + (dwp-1)
            f32x16 tmp = fz16;
#pragma unroll
            for (int ks = 0; ks < 4; ++ks) {
                s16x8 bfr = *(const s16x8*)&fe[rr][ks*2 + l5][col][0];
                tmp = __builtin_amdgcn_mfma_f32_32x32x16_bf16(aw[ks], bfr, tmp, 0, 0, 0);
            }
            float wsc = sw[rh][k9][half*32 + l31];
#pragma unroll
            for (int c = 0; c < 16; ++c) fin[half][c] += wsc * tmp[c];
        }
    }

    // --- epilogue: BN2 + ReLU, coalesced dword stores (128B segments) ---
    int obase = nt*32 + 4*l5;
#pragma unroll
    for (int half = 0; half < 2; ++half) {
        float* od = out + (((size_t)b*COUT + obase)*H_ + hC)*W_ + w0 + half*32 + l31;
#pragma unroll
        for (int v = 0; v < 4; ++v) {
            f32x4 sc4 = *(const f32x4*)&sbn[0][obase + 8*v];
            f32x4 tc4 = *(const f32x4*)&sbn[1][obase + 8*v];
#pragma unroll
            for (int c = 0; c < 4; ++c)
                od[(size_t)(8*v + c)*HWsz] =
                    fmaxf(fmaf(fin[half][4*v + c], sc4[c], tc4[c]), 0.f);
        }
    }
}

extern "C" void kernel_launch(void* const* d_in, const int* in_sizes, int n_in,
                              void* d_out, int out_size, void* d_ws, size_t ws_size,
                              hipStream_t stream)
{
    const float* x    = (const float*)d_in[0];
    const int*   mask = (const int*)d_in[1];
    const float* W1   = (const float*)d_in[2];
    const float* g1   = (const float*)d_in[3];
    const float* b1   = (const float*)d_in[4];
    const float* m1   = (const float*)d_in[5];
    const float* v1   = (const float*)d_in[6];
    const float* W2   = (const float*)d_in[7];
    const float* b2   = (const float*)d_in[8];
    const float* Wagg = (const float*)d_in[9];
    const float* g2   = (const float*)d_in[10];
    const float* bb2  = (const float*)d_in[11];
    const float* m2   = (const float*)d_in[12];
    const float* v2   = (const float*)d_in[13];
    float* outp = (float*)d_out;

    char* ws = (char*)d_ws;
    unsigned short* BwS   = (unsigned short*)(ws + 0);      // 73,728 B
    float*          Wfold = (float*)(ws + 73728);           //  2,052 B

    hipLaunchKernelGGL(prep_bw, dim3(18), dim3(256), 0, stream,
                       Wagg, W1, g1, b1, m1, v1, W2, BwS, Wfold);
    hipLaunchKernelGGL(mega_k, dim3(W_/64, 64), dim3(256), 0, stream,
                       x, mask, BwS, Wfold, b2, g2, bb2, m2, v2, outp);
}